// Round 1
// baseline (488.047 us; speedup 1.0000x reference)
//
#include <hip/hip_runtime.h>
#include <math.h>

#define N_  16
#define C_  128
#define T_  16384
#define K_  64
#define KG_ 73
#define TT  64
#define CT  512           // t-chunk per block
#define NCHUNK (T_/CT)    // 32 chunks per n -> 512 blocks
#define EPSN 1e-12f

#define XP 65   // xs pitch (odd -> strided LDS access is 2-way max = free)
#define LP 65   // lg pitch

// ---------------------------------------------------------------------------
// Kernel 1: fused normalize -> logits -> softmax -> VLAD partial accumulation
// ---------------------------------------------------------------------------
__global__ __launch_bounds__(256, 2)
void k_main(const float* __restrict__ x, const float* __restrict__ conv_w,
            float* __restrict__ gacc, float* __restrict__ gasum)
{
    __shared__ float xs[C_ * XP];               // 33280 B  [c][tl]
    __shared__ float lg[KG_ * LP];              // 18980 B  [k][tl] logits->exp
    __shared__ __align__(16) float st[TT * K_]; // 16384 B  [tl][k] soft (k<64)
    __shared__ float red [4 * TT];              // 1024 B   cross-wave partials
    __shared__ float red2[4 * TT];              // 1024 B
    __shared__ float rd[TT];                    // 256 B    1/denominator
    __shared__ float asq[4 * K_];               // 1024 B   a_sum partials

    const int tid  = threadIdx.x;
    const int lane = tid & 63;
    const int wv   = __builtin_amdgcn_readfirstlane(tid >> 6);
    const int bid  = blockIdx.x;
    const int n     = bid >> 5;
    const int chunk = bid & 31;
    const int tchunk0 = chunk * CT;

    float acc[32];
#pragma unroll
    for (int j = 0; j < 32; ++j) acc[j] = 0.f;
    float asum_reg = 0.f;

    // per-wave k range for logits: 19,18,18,18
    const int kbeg = (wv == 0) ? 0 : (1 + 18 * wv);
    const int kend = kbeg + ((wv == 0) ? 19 : 18);

    const int cV = tid & 127;   // vlad-phase channel owned by this thread
    const int k0 = 32 * __builtin_amdgcn_readfirstlane(tid >> 7);

    for (int it = 0; it < CT / TT; ++it) {
        const int tb = tchunk0 + it * TT;

        // ---- Phase L: stage x tile [128 c][64 t] (coalesced float4) ----
        for (int idx = tid; idx < C_ * (TT / 4); idx += 256) {
            const int t4 = idx & 15, c = idx >> 4;
            const float4 v = *reinterpret_cast<const float4*>(
                x + ((size_t)(n * C_ + c)) * T_ + tb + 4 * t4);
            float* p = &xs[c * XP + 4 * t4];
            p[0] = v.x; p[1] = v.y; p[2] = v.z; p[3] = v.w;
        }
        __syncthreads();

        // ---- Phase N: per-t L2 norm over c, scale xs in place ----
        {
            const int tl = tid & 63, q = tid >> 6;
            float s = 0.f;
            for (int c = 32 * q; c < 32 * q + 32; ++c) {
                const float v = xs[c * XP + tl];
                s += v * v;
            }
            red[q * TT + tl] = s;
            __syncthreads();
            const float tot = red[tl] + red[TT + tl] + red[2 * TT + tl] + red[3 * TT + tl];
            const float rn = 1.f / fmaxf(sqrtf(tot), EPSN);
            for (int c = 32 * q; c < 32 * q + 32; ++c) xs[c * XP + tl] *= rn;
        }
        __syncthreads();

        // ---- Phase S: logits = w @ xn, k-blocked by 8, w via scalar loads ----
        {
            const int tl = lane;
            for (int k8 = kbeg; k8 < kend; k8 += 8) {
                const int kn = kend - k8;  // 8,8,3(or 2)
                const float* wp[8];
#pragma unroll
                for (int j = 0; j < 8; ++j)
                    wp[j] = conv_w + (size_t)min(k8 + j, KG_ - 1) * C_;
                float la[8] = {0.f, 0.f, 0.f, 0.f, 0.f, 0.f, 0.f, 0.f};
                for (int c = 0; c < C_; ++c) {
                    const float v = xs[c * XP + tl];
#pragma unroll
                    for (int j = 0; j < 8; ++j) la[j] += v * wp[j][c];
                }
#pragma unroll
                for (int j = 0; j < 8; ++j)
                    if (j < kn) lg[(k8 + j) * LP + tl] = la[j];
            }
        }
        __syncthreads();

        // ---- Phase M: softmax over 73 k per t ----
        {
            const int tl = tid & 63, q = tid >> 6;
            const int kb = (q == 0) ? 0 : (1 + 18 * q);
            const int ke = kb + ((q == 0) ? 19 : 18);
            float m = -1e30f;
            for (int k = kb; k < ke; ++k) m = fmaxf(m, lg[k * LP + tl]);
            red[q * TT + tl] = m;
            __syncthreads();
            m = fmaxf(fmaxf(red[tl], red[TT + tl]),
                      fmaxf(red[2 * TT + tl], red[3 * TT + tl]));
            float s = 0.f;
            for (int k = kb; k < ke; ++k) {
                const float e = __expf(lg[k * LP + tl] - m);
                lg[k * LP + tl] = e;
                s += e;
            }
            red2[q * TT + tl] = s;
            __syncthreads();
            if (tid < 64) {
                const float d = red2[tid] + red2[TT + tid] + red2[2 * TT + tid] + red2[3 * TT + tid];
                rd[tid] = 1.f / d;
            }
            __syncthreads();
        }

        // ---- normalize + transpose to st[tl][k] (k<64) + a_sum accumulate ----
        {
            const int k = tid & 63, q = tid >> 6;
            float part = 0.f;
            for (int i = 0; i < 16; ++i) {
                const int tl = q * 16 + i;
                const float v = lg[k * LP + tl] * rd[tl];
                st[tl * K_ + k] = v;
                part += v;
            }
            asum_reg += part;
        }
        __syncthreads();

        // ---- Phase V: vlad[k][c] += soft[k][t] * xn[c][t] ----
        for (int tl = 0; tl < TT; ++tl) {
            const float xv = xs[cV * XP + tl];
            const float4* sp = reinterpret_cast<const float4*>(&st[tl * K_ + k0]);
#pragma unroll
            for (int jj = 0; jj < 8; ++jj) {
                const float4 s4 = sp[jj];
                acc[4 * jj + 0] += s4.x * xv;
                acc[4 * jj + 1] += s4.y * xv;
                acc[4 * jj + 2] += s4.z * xv;
                acc[4 * jj + 3] += s4.w * xv;
            }
        }
        __syncthreads();
    }

    // ---- write out partials ----
#pragma unroll
    for (int j = 0; j < 32; ++j)
        atomicAdd(&gacc[((size_t)n * K_ + (k0 + j)) * C_ + cV], acc[j]);

    {
        const int k = tid & 63, q = tid >> 6;
        asq[q * K_ + k] = asum_reg;
        __syncthreads();
        if (tid < 64) {
            const float s = asq[tid] + asq[K_ + tid] + asq[2 * K_ + tid] + asq[3 * K_ + tid];
            atomicAdd(&gasum[n * K_ + tid], s);
        }
    }
}

// ---------------------------------------------------------------------------
// Kernel 2a: per-(n,k) centroid subtract, intra-norm, *cw, write out, nsq
// ---------------------------------------------------------------------------
__global__ __launch_bounds__(64)
void k_post(const float* __restrict__ gacc, const float* __restrict__ gasum,
            const float* __restrict__ centroids, const float* __restrict__ cwv,
            float* __restrict__ out, float* __restrict__ nsq)
{
    const int b = blockIdx.x;       // n*64 + k
    const int n = b >> 6, k = b & 63;
    const int lane = threadIdx.x;

    // ||cluster_weights||
    const float cv = cwv[lane];
    float cs = cv * cv;
#pragma unroll
    for (int off = 32; off; off >>= 1) cs += __shfl_xor(cs, off);
    const float cwn = cwv[k] / fmaxf(sqrtf(cs), EPSN);

    const float asum = gasum[n * K_ + k];
    const float* ga = gacc + ((size_t)n * K_ + k) * C_;
    const float* ce = centroids + (size_t)k * C_;
    const float v0 = ga[lane]      - asum * ce[lane];
    const float v1 = ga[lane + 64] - asum * ce[lane + 64];
    float ss = v0 * v0 + v1 * v1;
#pragma unroll
    for (int off = 32; off; off >>= 1) ss += __shfl_xor(ss, off);
    const float scale = cwn / fmaxf(sqrtf(ss), EPSN);

    float* o = out + (size_t)n * (K_ * C_) + (size_t)k * C_;
    o[lane]      = v0 * scale;
    o[lane + 64] = v1 * scale;
    if (lane == 0) atomicAdd(&nsq[n], ss * scale * scale);
}

// ---------------------------------------------------------------------------
// Kernel 2b: global L2 normalize per n
// ---------------------------------------------------------------------------
__global__ __launch_bounds__(256)
void k_norm(float* __restrict__ out, const float* __restrict__ nsq)
{
    const int i = blockIdx.x * 256 + threadIdx.x;   // 131072 total
    const int n = i >> 13;
    const float r = 1.f / fmaxf(sqrtf(nsq[n]), EPSN);
    out[i] *= r;
}

// ---------------------------------------------------------------------------
extern "C" void kernel_launch(void* const* d_in, const int* in_sizes, int n_in,
                              void* d_out, int out_size, void* d_ws, size_t ws_size,
                              hipStream_t stream)
{
    const float* x         = (const float*)d_in[0];
    const float* conv_w    = (const float*)d_in[1];
    const float* centroids = (const float*)d_in[2];
    const float* cweights  = (const float*)d_in[3];
    float* out = (float*)d_out;

    float* gacc  = (float*)d_ws;            // [16][64][128]
    float* gasum = gacc + N_ * K_ * C_;     // [16][64]
    float* nsq   = gasum + N_ * K_;         // [16]
    const size_t zbytes = (size_t)(N_ * K_ * C_ + N_ * K_ + N_) * sizeof(float);

    hipMemsetAsync(d_ws, 0, zbytes, stream);
    hipLaunchKernelGGL(k_main, dim3(N_ * NCHUNK), dim3(256), 0, stream,
                       x, conv_w, gacc, gasum);
    hipLaunchKernelGGL(k_post, dim3(N_ * K_), dim3(64), 0, stream,
                       gacc, gasum, centroids, cweights, out, nsq);
    hipLaunchKernelGGL(k_norm, dim3(N_ * K_ * C_ / 256), dim3(256), 0, stream,
                       out, nsq);
}

// Round 2
// 433.903 us; speedup vs baseline: 1.1248x; 1.1248x over previous
//
#include <hip/hip_runtime.h>
#include <math.h>

#define N_  16
#define C_  128
#define T_  16384
#define K_  64
#define KG_ 73
#define TT  64
#define CT  512           // t-chunk per block -> 512 blocks = 2 blocks/CU
#define EPSN 1e-12f

#define XP 65   // xs pitch: (c*65+t)%32 = (c+t)%32 -> 2-way max on both row & col access
#define LP 65   // lg pitch

// ---------------------------------------------------------------------------
// Kernel 1: fused normalize -> logits+exp -> softmax-denom -> VLAD partials
// ---------------------------------------------------------------------------
__global__ __launch_bounds__(256, 2)
void k_main(const float* __restrict__ x, const float* __restrict__ conv_w,
            float* __restrict__ gacc, float* __restrict__ gasum)
{
    __shared__ float xs[C_ * XP];               // 33280 B  raw x tile [c][t]
    __shared__ float lg[KG_ * LP];              // 18980 B  exp(logit) [k][t]
    __shared__ __align__(16) float st[TT * K_]; // 16384 B  soft*rn    [t][k]
    __shared__ float red [4 * TT];              // sum-of-squares partials
    __shared__ float red2[4 * TT];              // exp-sum partials
    __shared__ float rd[TT];                    // 1/softmax-denominator
    __shared__ float rns[TT];                   // 1/||x_t||
    __shared__ float asq[4 * K_];               // a_sum partials

    const int tid  = threadIdx.x;
    const int lane = tid & 63;
    const int wv   = __builtin_amdgcn_readfirstlane(tid >> 6);
    const int n     = blockIdx.x >> 5;
    const int chunk = blockIdx.x & 31;
    const int t0    = chunk * CT;

    // per-wave k range for logits: 19,18,18,18 (covers 0..72)
    const int kbeg = (wv == 0) ? 0 : (1 + 18 * wv);
    const int kend = kbeg + ((wv == 0) ? 19 : 18);
    const int kO   = 16 * wv;   // V-phase k offset for this wave

    float acc0[16], acc1[16];
#pragma unroll
    for (int j = 0; j < 16; ++j) { acc0[j] = 0.f; acc1[j] = 0.f; }
    float asum_reg = 0.f;

    // staging: thread covers (c = tid>>4 + 16r, t4 = tid&15), r = 0..7
    const float* xbase = x + ((size_t)(n * C_ + (tid >> 4))) * T_ + 4 * (tid & 15);
    const int cst = tid >> 4, t4 = tid & 15;

    float4 pf[8];
#pragma unroll
    for (int r = 0; r < 8; ++r)
        pf[r] = *reinterpret_cast<const float4*>(xbase + (size_t)r * 16 * T_ + t0);

    for (int it = 0; it < 8; ++it) {
        // ---- store prefetched tile -> xs ----
#pragma unroll
        for (int r = 0; r < 8; ++r) {
            float* p = &xs[(cst + 16 * r) * XP + 4 * t4];
            p[0] = pf[r].x; p[1] = pf[r].y; p[2] = pf[r].z; p[3] = pf[r].w;
        }
        __syncthreads();                                        // B1: xs ready

        // ---- issue prefetch of next tile (hidden behind compute) ----
        if (it < 7) {
            const int tb = t0 + (it + 1) * TT;
#pragma unroll
            for (int r = 0; r < 8; ++r)
                pf[r] = *reinterpret_cast<const float4*>(xbase + (size_t)r * 16 * T_ + tb);
        }

        // ---- N: sum-of-squares partials (lane = t, wave = c-quarter) ----
        {
            float s = 0.f;
            for (int c = 32 * wv; c < 32 * wv + 32; ++c) {
                const float v = xs[c * XP + lane];
                s += v * v;
            }
            red[wv * TT + lane] = s;
        }
        __syncthreads();                                        // B2: red ready

        // ---- S: logits (scaled by rn) -> exp -> lg; per-wave exp-sum ----
        {
            const float tot = red[lane] + red[TT + lane] + red[2 * TT + lane] + red[3 * TT + lane];
            const float rn = 1.f / fmaxf(sqrtf(tot), EPSN);
            if (wv == 0) rns[lane] = rn;
            float esum = 0.f;
            for (int k8 = kbeg; k8 < kend; k8 += 8) {
                const int kn = kend - k8;   // 8,8,3 (or 2)
                const float* wp[8];
#pragma unroll
                for (int j = 0; j < 8; ++j)
                    wp[j] = conv_w + (size_t)min(k8 + j, KG_ - 1) * C_;
                float la[8] = {0.f, 0.f, 0.f, 0.f, 0.f, 0.f, 0.f, 0.f};
                for (int c = 0; c < C_; ++c) {
                    const float v = xs[c * XP + lane];
#pragma unroll
                    for (int j = 0; j < 8; ++j) la[j] += v * wp[j][c];
                }
#pragma unroll
                for (int j = 0; j < 8; ++j) {
                    if (j < kn) {
                        const float e = __expf(la[j] * rn);   // no max-subtract: |logit|<~14
                        lg[(k8 + j) * LP + lane] = e;
                        esum += e;
                    }
                }
            }
            red2[wv * TT + lane] = esum;
        }
        __syncthreads();                                        // B3: lg, red2 ready

        if (tid < TT) {
            const float d = red2[tid] + red2[TT + tid] + red2[2 * TT + tid] + red2[3 * TT + tid];
            rd[tid] = 1.f / d;
        }
        __syncthreads();                                        // B4: rd ready

        // ---- transpose: st[t][k] = soft * rn[t];  a_sum partial (unscaled) ----
        {
#pragma unroll
            for (int i = 0; i < 16; ++i) {
                const int tl = wv * 16 + i;
                const float v = lg[lane * LP + tl] * rd[tl];    // soft
                asum_reg += v;
                st[tl * K_ + lane] = v * rns[tl];
            }
        }
        __syncthreads();                                        // B5: st ready

        // ---- V: acc[k][c] += st(t,k) * xs(c,t)  (st already has rn folded) ----
        {
            const float* x0p = &xs[lane * XP];
            const float* x1p = &xs[(lane + 64) * XP];
            for (int tl = 0; tl < TT; ++tl) {
                const float x0 = x0p[tl];
                const float x1 = x1p[tl];
                const float4* sp = reinterpret_cast<const float4*>(&st[tl * K_ + kO]);
#pragma unroll
                for (int jj = 0; jj < 4; ++jj) {
                    const float4 s4 = sp[jj];
                    acc0[4 * jj + 0] += s4.x * x0;  acc1[4 * jj + 0] += s4.x * x1;
                    acc0[4 * jj + 1] += s4.y * x0;  acc1[4 * jj + 1] += s4.y * x1;
                    acc0[4 * jj + 2] += s4.z * x0;  acc1[4 * jj + 2] += s4.z * x1;
                    acc0[4 * jj + 3] += s4.w * x0;  acc1[4 * jj + 3] += s4.w * x1;
                }
            }
        }
        __syncthreads();                                        // B6: xs/st consumed
    }

    // ---- write out partials (coalesced over c) ----
#pragma unroll
    for (int j = 0; j < 16; ++j) {
        atomicAdd(&gacc[((size_t)n * K_ + (kO + j)) * C_ + lane],      acc0[j]);
        atomicAdd(&gacc[((size_t)n * K_ + (kO + j)) * C_ + lane + 64], acc1[j]);
    }
    asq[wv * K_ + lane] = asum_reg;
    __syncthreads();
    if (tid < K_) {
        const float s = asq[tid] + asq[K_ + tid] + asq[2 * K_ + tid] + asq[3 * K_ + tid];
        atomicAdd(&gasum[n * K_ + tid], s);
    }
}

// ---------------------------------------------------------------------------
// Kernel 2a: per-(n,k) centroid subtract, intra-norm, *cw, write out, nsq
// ---------------------------------------------------------------------------
__global__ __launch_bounds__(64)
void k_post(const float* __restrict__ gacc, const float* __restrict__ gasum,
            const float* __restrict__ centroids, const float* __restrict__ cwv,
            float* __restrict__ out, float* __restrict__ nsq)
{
    const int b = blockIdx.x;       // n*64 + k
    const int n = b >> 6, k = b & 63;
    const int lane = threadIdx.x;

    const float cv = cwv[lane];
    float cs = cv * cv;
#pragma unroll
    for (int off = 32; off; off >>= 1) cs += __shfl_xor(cs, off);
    const float cwn = cwv[k] / fmaxf(sqrtf(cs), EPSN);

    const float asum = gasum[n * K_ + k];
    const float* ga = gacc + ((size_t)n * K_ + k) * C_;
    const float* ce = centroids + (size_t)k * C_;
    const float v0 = ga[lane]      - asum * ce[lane];
    const float v1 = ga[lane + 64] - asum * ce[lane + 64];
    float ss = v0 * v0 + v1 * v1;
#pragma unroll
    for (int off = 32; off; off >>= 1) ss += __shfl_xor(ss, off);
    const float scale = cwn / fmaxf(sqrtf(ss), EPSN);

    float* o = out + (size_t)n * (K_ * C_) + (size_t)k * C_;
    o[lane]      = v0 * scale;
    o[lane + 64] = v1 * scale;
    if (lane == 0) atomicAdd(&nsq[n], ss * scale * scale);
}

// ---------------------------------------------------------------------------
// Kernel 2b: global L2 normalize per n
// ---------------------------------------------------------------------------
__global__ __launch_bounds__(256)
void k_norm(float* __restrict__ out, const float* __restrict__ nsq)
{
    const int i = blockIdx.x * 256 + threadIdx.x;   // 131072 total
    const int n = i >> 13;
    const float r = 1.f / fmaxf(sqrtf(nsq[n]), EPSN);
    out[i] *= r;
}

// ---------------------------------------------------------------------------
extern "C" void kernel_launch(void* const* d_in, const int* in_sizes, int n_in,
                              void* d_out, int out_size, void* d_ws, size_t ws_size,
                              hipStream_t stream)
{
    const float* x         = (const float*)d_in[0];
    const float* conv_w    = (const float*)d_in[1];
    const float* centroids = (const float*)d_in[2];
    const float* cweights  = (const float*)d_in[3];
    float* out = (float*)d_out;

    float* gacc  = (float*)d_ws;            // [16][64][128]
    float* gasum = gacc + N_ * K_ * C_;     // [16][64]
    float* nsq   = gasum + N_ * K_;         // [16]
    const size_t zbytes = (size_t)(N_ * K_ * C_ + N_ * K_ + N_) * sizeof(float);

    hipMemsetAsync(d_ws, 0, zbytes, stream);
    hipLaunchKernelGGL(k_main, dim3(N_ * (T_ / CT)), dim3(256), 0, stream,
                       x, conv_w, gacc, gasum);
    hipLaunchKernelGGL(k_post, dim3(N_ * K_), dim3(64), 0, stream,
                       gacc, gasum, centroids, cweights, out, nsq);
    hipLaunchKernelGGL(k_norm, dim3(N_ * K_ * C_ / 256), dim3(256), 0, stream,
                       out, nsq);
}

// Round 3
// 229.251 us; speedup vs baseline: 2.1289x; 1.8927x over previous
//
#include <hip/hip_runtime.h>
#include <math.h>

#define N_  16
#define C_  128
#define T_  16384
#define K_  64
#define KG_ 73
#define CT  512           // t-chunk per block -> 512 blocks
#define EPSN 1e-12f
#define P1  72            // xb pitch (bf16): 144B rows, 16B-aligned
#define P2  72            // st pitch (bf16)

typedef __bf16 bf16x4v __attribute__((ext_vector_type(4)));
typedef __bf16 bf16x8v __attribute__((ext_vector_type(8)));
typedef float  f32x4v  __attribute__((ext_vector_type(4)));

#define MFMA(a, b, c) __builtin_amdgcn_mfma_f32_16x16x32_bf16((a), (b), (c), 0, 0, 0)

// ---------------------------------------------------------------------------
// Kernel 1: fused normalize -> logits (MFMA) -> softmax -> VLAD (MFMA) partials
//   x tile staged once as bf16 [c][t] with t-index swizzle t' = t ^ 8*((c>>3)&3)
//   GEMM1: Lt[t, cl] = X[t,c] @ W^T   (A = x gathered b16, B = W in regs)
//   GEMM2: V[cl, c] += S[cl,t] @ X^T  (A = soft*rn from st, B = x b128 reads)
// ---------------------------------------------------------------------------
__global__ __launch_bounds__(256, 2)
void k_main(const float* __restrict__ x, const float* __restrict__ conv_w,
            float* __restrict__ gacc, float* __restrict__ gasum)
{
    __shared__ __align__(16) __bf16 xb[C_ * P1];   // 18432 B  raw x bf16 [c][t-swizzled]
    __shared__ __align__(16) __bf16 st[K_ * P2];   //  9216 B  soft*rn bf16 [cl][t]

    const int tid  = threadIdx.x;
    const int lane = tid & 63;
    const int wv   = __builtin_amdgcn_readfirstlane(tid >> 6);
    const int q    = lane >> 4;       // lane quarter
    const int l15  = lane & 15;
    const int n    = blockIdx.x >> 5;
    const int t0   = (blockIdx.x & 31) * CT;

    // ---- preload W B-fragments: wf[nt][ks], cl = 16nt+l15, c = 32ks+8q+j ----
    bf16x8v wf[5][4];
#pragma unroll
    for (int nt = 0; nt < 5; ++nt) {
        const int row = min(16 * nt + l15, KG_ - 1);   // clamp ghost rows >=73 (masked later)
#pragma unroll
        for (int ks = 0; ks < 4; ++ks) {
            const float* wp = conv_w + (size_t)row * C_ + 32 * ks + 8 * q;
            const float4 w0 = *(const float4*)wp;
            const float4 w1 = *(const float4*)(wp + 4);
            bf16x8v f;
            f[0] = (__bf16)w0.x; f[1] = (__bf16)w0.y; f[2] = (__bf16)w0.z; f[3] = (__bf16)w0.w;
            f[4] = (__bf16)w1.x; f[5] = (__bf16)w1.y; f[6] = (__bf16)w1.z; f[7] = (__bf16)w1.w;
            wf[nt][ks] = f;
        }
    }

    f32x4v acc2[8];                    // VLAD accumulators: cl-tile wv x 8 c-tiles
#pragma unroll
    for (int i = 0; i < 8; ++i) acc2[i] = (f32x4v){0.f, 0.f, 0.f, 0.f};
    float asum_acc[4] = {0.f, 0.f, 0.f, 0.f};

    // staging: thread covers (c = cst+16r, t = 4*t4..4*t4+3), r = 0..7
    const int cst = tid >> 4, t4 = tid & 15;
    const float* xbase = x + ((size_t)(n * C_ + cst)) * T_ + 4 * t4;

    float4 pf[8];
#pragma unroll
    for (int r = 0; r < 8; ++r)
        pf[r] = *(const float4*)(xbase + (size_t)r * 16 * T_ + t0);

    for (int it = 0; it < 8; ++it) {
        // ---- stage prefetched tile -> xb (bf16, swizzled), b64 writes ----
#pragma unroll
        for (int r = 0; r < 8; ++r) {
            const int c  = cst + 16 * r;
            const int s8 = 8 * (((cst >> 3) + 2 * r) & 3);   // = 8*((c>>3)&3)
            bf16x4v v = { (__bf16)pf[r].x, (__bf16)pf[r].y, (__bf16)pf[r].z, (__bf16)pf[r].w };
            *(bf16x4v*)&xb[c * P1 + ((4 * t4) ^ s8)] = v;
        }
        __syncthreads();                                     // B1: xb ready

        // ---- prefetch next tile ----
        if (it < 7) {
            const int tb = t0 + (it + 1) * 64;
#pragma unroll
            for (int r = 0; r < 8; ++r)
                pf[r] = *(const float4*)(xbase + (size_t)r * 16 * T_ + tb);
        }

        // ---- GEMM1 + Gram: Lt[t=16wv+l15][cl] ; diag(X X^T) for ||x_t||^2 ----
        f32x4v acc1[5];
#pragma unroll
        for (int i = 0; i < 5; ++i) acc1[i] = (f32x4v){0.f, 0.f, 0.f, 0.f};
        f32x4v gr = (f32x4v){0.f, 0.f, 0.f, 0.f};

        const int tq = (16 * wv + l15) ^ (8 * q);            // swizzled t for c-block q
#pragma unroll
        for (int ks = 0; ks < 4; ++ks) {
            const __bf16* base = &xb[(32 * ks + 8 * q) * P1 + tq];
            bf16x8v af;
            af[0] = base[0 * P1]; af[1] = base[1 * P1];
            af[2] = base[2 * P1]; af[3] = base[3 * P1];
            af[4] = base[4 * P1]; af[5] = base[5 * P1];
            af[6] = base[6 * P1]; af[7] = base[7 * P1];
            gr = MFMA(af, af, gr);
#pragma unroll
            for (int nt = 0; nt < 5; ++nt)
                acc1[nt] = MFMA(af, wf[nt][ks], acc1[nt]);
        }

        // ---- rn_t from Gram diag via bpermute (t = 16wv + 4q + r) ----
        float rn[4];
#pragma unroll
        for (int r = 0; r < 4; ++r) {
            const float ss = __int_as_float(
                __builtin_amdgcn_ds_bpermute((20 * q + r) << 2, __float_as_int(gr[r])));
            rn[r] = 1.f / fmaxf(sqrtf(ss), EPSN);
        }

        // ---- softmax over 73 clusters, fully in registers ----
        float e[5][4];
        float d[4] = {0.f, 0.f, 0.f, 0.f};
#pragma unroll
        for (int nt = 0; nt < 5; ++nt) {
            const bool valid = (16 * nt + l15) < KG_;
#pragma unroll
            for (int r = 0; r < 4; ++r) {
                const float ev = __expf(acc1[nt][r] * rn[r]);   // |logit| <= ~13, no max needed
                const float evm = valid ? ev : 0.f;
                e[nt][r] = evm;
                d[r] += evm;
            }
        }
#pragma unroll
        for (int r = 0; r < 4; ++r) {
            d[r] += __shfl_xor(d[r], 1);
            d[r] += __shfl_xor(d[r], 2);
            d[r] += __shfl_xor(d[r], 4);
            d[r] += __shfl_xor(d[r], 8);
            d[r] = 1.f / d[r];
        }

        // ---- soft -> st[cl][t] (rn folded), a_sum accumulate (fp32) ----
#pragma unroll
        for (int nt = 0; nt < 4; ++nt) {
            bf16x4v sv;
            float ap = 0.f;
#pragma unroll
            for (int r = 0; r < 4; ++r) {
                const float s = e[nt][r] * d[r];
                ap += s;
                sv[r] = (__bf16)(s * rn[r]);
            }
            asum_acc[nt] += ap;
            *(bf16x4v*)&st[(16 * nt + l15) * P2 + 16 * wv + 4 * q] = sv;
        }
        __syncthreads();                                     // B2: st ready

        // ---- GEMM2: V[cl = 16wv+..][c] += S @ X^T ----
        bf16x8v sa0 = *(const bf16x8v*)&st[(16 * wv + l15) * P2 +      8 * q];
        bf16x8v sa1 = *(const bf16x8v*)&st[(16 * wv + l15) * P2 + 32 + 8 * q];
#pragma unroll
        for (int nt2 = 0; nt2 < 8; ++nt2) {
            const int c = 16 * nt2 + l15;
            const int s = (2 * nt2 + (l15 >> 3)) & 3;        // (c>>3)&3
            const bf16x8v xf0 = *(const bf16x8v*)&xb[c * P1 +      8 * (q ^ s)];
            const bf16x8v xf1 = *(const bf16x8v*)&xb[c * P1 + 32 + 8 * (q ^ s)];
            acc2[nt2] = MFMA(sa0, xf0, acc2[nt2]);
            acc2[nt2] = MFMA(sa1, xf1, acc2[nt2]);
        }
        __syncthreads();                                     // B3: xb/st consumed
    }

    // ---- write VLAD partials: lane holds V[16wv+4q+r][16nt2+l15] ----
#pragma unroll
    for (int nt2 = 0; nt2 < 8; ++nt2)
#pragma unroll
        for (int r = 0; r < 4; ++r)
            atomicAdd(&gacc[((size_t)n * K_ + (16 * wv + 4 * q + r)) * C_ + 16 * nt2 + l15],
                      acc2[nt2][r]);

    // ---- a_sum partials: reduce over q, one atomic per (cl, wave) ----
#pragma unroll
    for (int nt = 0; nt < 4; ++nt) {
        float v = asum_acc[nt];
        v += __shfl_xor(v, 16);
        v += __shfl_xor(v, 32);
        if (q == 0) atomicAdd(&gasum[n * K_ + 16 * nt + l15], v);
    }
}

// ---------------------------------------------------------------------------
// Kernel 2a: per-(n,k) centroid subtract, intra-norm, *cw, write out, nsq
// ---------------------------------------------------------------------------
__global__ __launch_bounds__(64)
void k_post(const float* __restrict__ gacc, const float* __restrict__ gasum,
            const float* __restrict__ centroids, const float* __restrict__ cwv,
            float* __restrict__ out, float* __restrict__ nsq)
{
    const int b = blockIdx.x;       // n*64 + k
    const int n = b >> 6, k = b & 63;
    const int lane = threadIdx.x;

    const float cv = cwv[lane];
    float cs = cv * cv;
#pragma unroll
    for (int off = 32; off; off >>= 1) cs += __shfl_xor(cs, off);
    const float cwn = cwv[k] / fmaxf(sqrtf(cs), EPSN);

    const float asum = gasum[n * K_ + k];
    const float* ga = gacc + ((size_t)n * K_ + k) * C_;
    const float* ce = centroids + (size_t)k * C_;
    const float v0 = ga[lane]      - asum * ce[lane];
    const float v1 = ga[lane + 64] - asum * ce[lane + 64];
    float ss = v0 * v0 + v1 * v1;
#pragma unroll
    for (int off = 32; off; off >>= 1) ss += __shfl_xor(ss, off);
    const float scale = cwn / fmaxf(sqrtf(ss), EPSN);

    float* o = out + (size_t)n * (K_ * C_) + (size_t)k * C_;
    o[lane]      = v0 * scale;
    o[lane + 64] = v1 * scale;
    if (lane == 0) atomicAdd(&nsq[n], ss * scale * scale);
}

// ---------------------------------------------------------------------------
// Kernel 2b: global L2 normalize per n
// ---------------------------------------------------------------------------
__global__ __launch_bounds__(256)
void k_norm(float* __restrict__ out, const float* __restrict__ nsq)
{
    const int i = blockIdx.x * 256 + threadIdx.x;   // 131072 total
    const int n = i >> 13;
    const float r = 1.f / fmaxf(sqrtf(nsq[n]), EPSN);
    out[i] *= r;
}

// ---------------------------------------------------------------------------
extern "C" void kernel_launch(void* const* d_in, const int* in_sizes, int n_in,
                              void* d_out, int out_size, void* d_ws, size_t ws_size,
                              hipStream_t stream)
{
    const float* x         = (const float*)d_in[0];
    const float* conv_w    = (const float*)d_in[1];
    const float* centroids = (const float*)d_in[2];
    const float* cweights  = (const float*)d_in[3];
    float* out = (float*)d_out;

    float* gacc  = (float*)d_ws;            // [16][64][128]
    float* gasum = gacc + N_ * K_ * C_;     // [16][64]
    float* nsq   = gasum + N_ * K_;         // [16]
    const size_t zbytes = (size_t)(N_ * K_ * C_ + N_ * K_ + N_) * sizeof(float);

    hipMemsetAsync(d_ws, 0, zbytes, stream);
    hipLaunchKernelGGL(k_main, dim3(N_ * (T_ / CT)), dim3(256), 0, stream,
                       x, conv_w, gacc, gasum);
    hipLaunchKernelGGL(k_post, dim3(N_ * K_), dim3(64), 0, stream,
                       gacc, gasum, centroids, cweights, out, nsq);
    hipLaunchKernelGGL(k_norm, dim3(N_ * K_ * C_ / 256), dim3(256), 0, stream,
                       out, nsq);
}

// Round 4
// 228.132 us; speedup vs baseline: 2.1393x; 1.0049x over previous
//
#include <hip/hip_runtime.h>
#include <math.h>

#define N_  16
#define C_  128
#define T_  16384
#define K_  64
#define KG_ 73
#define CT  512           // t-chunk per block -> 512 blocks = 2 blocks/CU
#define NCH 32            // chunks per n
#define EPSN 1e-12f
#define P1  72            // xb pitch (bf16): 36 dwords -> 8 bank-groups for b128 reads
#define P2  72            // st pitch (bf16)

typedef __bf16 bf16x4v __attribute__((ext_vector_type(4)));
typedef __bf16 bf16x8v __attribute__((ext_vector_type(8)));
typedef float  f32x4v  __attribute__((ext_vector_type(4)));

#define MFMA(a, b, c) __builtin_amdgcn_mfma_f32_16x16x32_bf16((a), (b), (c), 0, 0, 0)

// ---------------------------------------------------------------------------
// Kernel 1: fused normalize -> logits (MFMA, A from global) -> softmax ->
//           VLAD (MFMA, LDS) -> per-chunk partials (NO atomics)
// ---------------------------------------------------------------------------
__global__ __launch_bounds__(256, 2)
void k_main(const float* __restrict__ x, const float* __restrict__ conv_w,
            float* __restrict__ gaccp, float* __restrict__ gasump)
{
    __shared__ __align__(16) __bf16 xb[2][C_ * P1];   // 2 x 18432 B  x bf16 [c][t]
    __shared__ __align__(16) __bf16 st[2][K_ * P2];   // 2 x  9216 B  soft*rn [cl][t]
    __shared__ float asq[4 * K_];                     // a_sum partials

    const int tid  = threadIdx.x;
    const int lane = tid & 63;
    const int wv   = __builtin_amdgcn_readfirstlane(tid >> 6);
    const int q    = lane >> 4;
    const int l15  = lane & 15;
    const int n     = blockIdx.x >> 5;
    const int chunk = blockIdx.x & 31;
    const int t0    = chunk * CT;

    // ---- preload W B-fragments: wf[nt][ks], cl = 16nt+l15, c = 32ks+8q+j ----
    bf16x8v wf[5][4];
#pragma unroll
    for (int nt = 0; nt < 5; ++nt) {
        const int row = min(16 * nt + l15, KG_ - 1);   // ghost rows >=73 masked later
#pragma unroll
        for (int ks = 0; ks < 4; ++ks) {
            const float* wp = conv_w + (size_t)row * C_ + 32 * ks + 8 * q;
            const float4 w0 = *(const float4*)wp;
            const float4 w1 = *(const float4*)(wp + 4);
            bf16x8v f;
            f[0] = (__bf16)w0.x; f[1] = (__bf16)w0.y; f[2] = (__bf16)w0.z; f[3] = (__bf16)w0.w;
            f[4] = (__bf16)w1.x; f[5] = (__bf16)w1.y; f[6] = (__bf16)w1.z; f[7] = (__bf16)w1.w;
            wf[nt][ks] = f;
        }
    }

    f32x4v acc2[8];                    // VLAD accumulators: 2 cl-blocks x 4 c-blocks
#pragma unroll
    for (int i = 0; i < 8; ++i) acc2[i] = (f32x4v){0.f, 0.f, 0.f, 0.f};
    float asum_acc[4] = {0.f, 0.f, 0.f, 0.f};

    // staging: thread covers (c = cst+16r, t = 4*t4..4*t4+3), r = 0..7
    const int cst = tid >> 4, t4 = tid & 15;
    const float* xbase = x + ((size_t)(n * C_ + cst)) * T_ + 4 * t4;

    // GEMM1 A-frag global base: lane reads x[32ks+8q+j][t0+64it+16wv+l15]
    const float* g1 = x + ((size_t)(n * C_ + 8 * q)) * T_ + t0 + 16 * wv + l15;

    float4 pf[8];
#pragma unroll
    for (int r = 0; r < 8; ++r)
        pf[r] = *(const float4*)(xbase + (size_t)r * 16 * T_ + t0);

    int p = 0;
    for (int it = 0; it < 8; ++it) {
        // ---- stage prefetched tile -> xb[p] (bf16, b64 writes) ----
#pragma unroll
        for (int r = 0; r < 8; ++r) {
            bf16x4v v = { (__bf16)pf[r].x, (__bf16)pf[r].y, (__bf16)pf[r].z, (__bf16)pf[r].w };
            *(bf16x4v*)&xb[p][(cst + 16 * r) * P1 + 4 * t4] = v;
        }

        // ---- prefetch next tile ----
        if (it < 7) {
            const int tb = t0 + (it + 1) * 64;
#pragma unroll
            for (int r = 0; r < 8; ++r)
                pf[r] = *(const float4*)(xbase + (size_t)r * 16 * T_ + tb);
        }

        // ---- GEMM1 + Gram, A-frags straight from global (L1/L2-hot lines) ----
        f32x4v acc1[5];
#pragma unroll
        for (int i = 0; i < 5; ++i) acc1[i] = (f32x4v){0.f, 0.f, 0.f, 0.f};
        f32x4v gr = (f32x4v){0.f, 0.f, 0.f, 0.f};

#pragma unroll
        for (int ks = 0; ks < 4; ++ks) {
            const float* gp = g1 + ((size_t)(32 * ks)) * T_ + it * 64;
            bf16x8v af;
#pragma unroll
            for (int j = 0; j < 8; ++j) af[j] = (__bf16)gp[(size_t)j * T_];
            gr = MFMA(af, af, gr);
#pragma unroll
            for (int nt = 0; nt < 5; ++nt)
                acc1[nt] = MFMA(af, wf[nt][ks], acc1[nt]);
        }

        // ---- rn_t from Gram diag via bpermute (t = 16wv + 4q + r) ----
        float rn[4];
#pragma unroll
        for (int r = 0; r < 4; ++r) {
            const float ss = __int_as_float(
                __builtin_amdgcn_ds_bpermute((20 * q + r) << 2, __float_as_int(gr[r])));
            rn[r] = 1.f / fmaxf(sqrtf(ss), EPSN);
        }

        // ---- softmax over 73 clusters, fully in registers ----
        float e[5][4];
        float d[4] = {0.f, 0.f, 0.f, 0.f};
#pragma unroll
        for (int nt = 0; nt < 5; ++nt) {
            const bool valid = (16 * nt + l15) < KG_;
#pragma unroll
            for (int r = 0; r < 4; ++r) {
                const float ev = __expf(acc1[nt][r] * rn[r]);   // |logit| <= ~13
                e[nt][r] = valid ? ev : 0.f;
                d[r] += e[nt][r];
            }
        }
#pragma unroll
        for (int r = 0; r < 4; ++r) {
            d[r] += __shfl_xor(d[r], 1);
            d[r] += __shfl_xor(d[r], 2);
            d[r] += __shfl_xor(d[r], 4);
            d[r] += __shfl_xor(d[r], 8);
            d[r] = 1.f / d[r];
        }

        // ---- soft -> st[p][cl][t] (rn folded), a_sum accumulate (fp32) ----
#pragma unroll
        for (int nt = 0; nt < 4; ++nt) {
            bf16x4v sv;
            float ap = 0.f;
#pragma unroll
            for (int r = 0; r < 4; ++r) {
                const float s = e[nt][r] * d[r];
                ap += s;
                sv[r] = (__bf16)(s * rn[r]);
            }
            asum_acc[nt] += ap;
            *(bf16x4v*)&st[p][(16 * nt + l15) * P2 + 16 * wv + 4 * q] = sv;
        }
        __syncthreads();                     // ONE barrier/tile: xb[p], st[p] ready

        // ---- GEMM2: wave covers 2 cl-blocks x 4 c-blocks ----
        {
            const int clp = wv >> 1;         // cl pair: blocks {2clp, 2clp+1}
            const int chh = wv & 1;          // c half:  blocks {4chh..4chh+3}
            bf16x8v sa[2][2];
#pragma unroll
            for (int clb = 0; clb < 2; ++clb)
#pragma unroll
                for (int ks2 = 0; ks2 < 2; ++ks2)
                    sa[clb][ks2] = *(const bf16x8v*)
                        &st[p][(16 * (2 * clp + clb) + l15) * P2 + 32 * ks2 + 8 * q];
#pragma unroll
            for (int cb = 0; cb < 4; ++cb) {
                const int c = 16 * (4 * chh + cb) + l15;
                const bf16x8v xf0 = *(const bf16x8v*)&xb[p][c * P1 + 8 * q];
                const bf16x8v xf1 = *(const bf16x8v*)&xb[p][c * P1 + 32 + 8 * q];
                acc2[cb]     = MFMA(sa[0][0], xf0, acc2[cb]);
                acc2[cb]     = MFMA(sa[0][1], xf1, acc2[cb]);
                acc2[4 + cb] = MFMA(sa[1][0], xf0, acc2[4 + cb]);
                acc2[4 + cb] = MFMA(sa[1][1], xf1, acc2[4 + cb]);
            }
        }
        p ^= 1;
    }

    // ---- write per-chunk VLAD partials (plain stores, no atomics) ----
    {
        const int clp = wv >> 1, chh = wv & 1;
        float* gp = gaccp + ((size_t)(n * NCH + chunk) * K_) * C_;
#pragma unroll
        for (int clb = 0; clb < 2; ++clb)
#pragma unroll
            for (int cb = 0; cb < 4; ++cb)
#pragma unroll
                for (int r = 0; r < 4; ++r) {
                    const int cl = 16 * (2 * clp + clb) + 4 * q + r;
                    const int c  = 16 * (4 * chh + cb) + l15;
                    gp[cl * C_ + c] = acc2[clb * 4 + cb][r];
                }
    }

    // ---- a_sum per-chunk partials ----
#pragma unroll
    for (int nt = 0; nt < 4; ++nt) {
        float v = asum_acc[nt];
        v += __shfl_xor(v, 16);
        v += __shfl_xor(v, 32);
        if (q == 0) asq[wv * K_ + 16 * nt + l15] = v;
    }
    __syncthreads();
    if (tid < K_) {
        const float s = asq[tid] + asq[K_ + tid] + asq[2 * K_ + tid] + asq[3 * K_ + tid];
        gasump[(n * NCH + chunk) * K_ + tid] = s;
    }
}

// ---------------------------------------------------------------------------
// Kernel 2a: reduce chunk partials, centroid subtract, intra-norm, *cw, nsq
// ---------------------------------------------------------------------------
__global__ __launch_bounds__(64)
void k_post(const float* __restrict__ gaccp, const float* __restrict__ gasump,
            const float* __restrict__ centroids, const float* __restrict__ cwv,
            float* __restrict__ out, float* __restrict__ nsq)
{
    const int b = blockIdx.x;       // n*64 + k
    const int n = b >> 6, k = b & 63;
    const int lane = threadIdx.x;

    const float cv = cwv[lane];
    float cs = cv * cv;
#pragma unroll
    for (int off = 32; off; off >>= 1) cs += __shfl_xor(cs, off);
    const float cwn = cwv[k] / fmaxf(sqrtf(cs), EPSN);

    // reduce 32 chunk partials
    float v0 = 0.f, v1 = 0.f;
    const float* gp = gaccp + ((size_t)(n * NCH) * K_ + k) * C_;
    for (int ch = 0; ch < NCH; ++ch) {
        v0 += gp[lane];
        v1 += gp[lane + 64];
        gp += K_ * C_;
    }
    float asum = 0.f;
    const float* gs = gasump + (size_t)(n * NCH) * K_ + k;
    for (int ch = 0; ch < NCH; ++ch) asum += gs[ch * K_];   // uniform -> s_loads

    const float* ce = centroids + (size_t)k * C_;
    v0 -= asum * ce[lane];
    v1 -= asum * ce[lane + 64];
    float ss = v0 * v0 + v1 * v1;
#pragma unroll
    for (int off = 32; off; off >>= 1) ss += __shfl_xor(ss, off);
    const float scale = cwn / fmaxf(sqrtf(ss), EPSN);

    float* o = out + (size_t)n * (K_ * C_) + (size_t)k * C_;
    o[lane]      = v0 * scale;
    o[lane + 64] = v1 * scale;
    if (lane == 0) atomicAdd(&nsq[n], ss * scale * scale);
}

// ---------------------------------------------------------------------------
// Kernel 2b: global L2 normalize per n
// ---------------------------------------------------------------------------
__global__ __launch_bounds__(256)
void k_norm(float* __restrict__ out, const float* __restrict__ nsq)
{
    const int i = blockIdx.x * 256 + threadIdx.x;   // 131072 total
    const int n = i >> 13;
    const float r = 1.f / fmaxf(sqrtf(nsq[n]), EPSN);
    out[i] *= r;
}

// ---------------------------------------------------------------------------
extern "C" void kernel_launch(void* const* d_in, const int* in_sizes, int n_in,
                              void* d_out, int out_size, void* d_ws, size_t ws_size,
                              hipStream_t stream)
{
    const float* x         = (const float*)d_in[0];
    const float* conv_w    = (const float*)d_in[1];
    const float* centroids = (const float*)d_in[2];
    const float* cweights  = (const float*)d_in[3];
    float* out = (float*)d_out;

    float* nsq    = (float*)d_ws;                    // [16]
    float* gasump = nsq + 16;                        // [16*32][64]
    float* gaccp  = gasump + N_ * NCH * K_;          // [16*32][64][128] = 16 MB

    hipMemsetAsync(nsq, 0, N_ * sizeof(float), stream);
    hipLaunchKernelGGL(k_main, dim3(N_ * NCH), dim3(256), 0, stream,
                       x, conv_w, gaccp, gasump);
    hipLaunchKernelGGL(k_post, dim3(N_ * K_), dim3(64), 0, stream,
                       gaccp, gasump, centroids, cweights, out, nsq);
    hipLaunchKernelGGL(k_norm, dim3(N_ * K_ * C_ / 256), dim3(256), 0, stream,
                       out, nsq);
}